// Round 2
// baseline (1517.898 us; speedup 1.0000x reference)
//
#include <hip/hip_runtime.h>

typedef unsigned short u16;
typedef unsigned int u32;
typedef float f32x4 __attribute__((ext_vector_type(4)));
typedef short short8 __attribute__((ext_vector_type(8)));

#define DIM 128
#define NUM_NODE 43097
#define NV (NUM_NODE - 1)      // 43096 score columns
#define BB 4096
#define LL 50
#define NN (BB * LL)           // 204800 item nodes
#define EE (NN * 4)            // 819200 interact edges

__device__ __forceinline__ float b2f(u16 u) {
    union { u32 u; float f; } x; x.u = ((u32)u) << 16; return x.f;
}
__device__ __forceinline__ u16 f2b(float f) {
    union { float f; u32 u; } x; x.f = f;
    u32 r = x.u + 0x7FFFu + ((x.u >> 16) & 1u);
    return (u16)(r >> 16);
}

// ---------------- K0: fp32 -> bf16 conversion (pairs) ----------------------
__global__ __launch_bounds__(256) void k_cvt(
    const float* __restrict__ s, u16* __restrict__ d, int n2)
{
    int i = blockIdx.x * 256 + threadIdx.x;
    if (i < n2) {
        float2 v = ((const float2*)s)[i];
        ((u32*)d)[i] = (u32)f2b(v.x) | ((u32)f2b(v.y) << 16);
    }
}

// ---------------- K1: edge logits + deg count (wave per edge) --------------
__global__ __launch_bounds__(256) void k_edge_logits(
    const u16* __restrict__ emb_bf, const float* __restrict__ pi_w,
    const int* __restrict__ iid, const int* __restrict__ int_src,
    const int* __restrict__ int_dst, float* __restrict__ logits,
    int* __restrict__ deg)
{
    int e = blockIdx.x * 4 + (threadIdx.x >> 6);
    int lane = threadIdx.x & 63;
    int s = int_src[e], d = int_dst[e];
    int sr = iid[s], dr = iid[d];
    ushort2 a = ((const ushort2*)(emb_bf + (size_t)sr * DIM))[lane];
    ushort2 b = ((const ushort2*)(emb_bf + (size_t)dr * DIM))[lane];
    float2 w = ((const float2*)pi_w)[lane];
    float part = b2f(a.x) * w.x * b2f(b.x) + b2f(a.y) * w.y * b2f(b.y);
    #pragma unroll
    for (int o = 32; o; o >>= 1) part += __shfl_xor(part, o, 64);
    if (lane == 0) {
        float lr = part >= 0.f ? part : 0.2f * part;   // leaky_relu 0.2
        logits[e] = lr;
        atomicAdd(&deg[d], 1);
    }
}

// ---------------- K2: exclusive scan of deg (3 kernels) --------------------
__global__ void k_block_sum(const int* __restrict__ deg, int* __restrict__ bsum)
{
    __shared__ int sm[256];
    int i = blockIdx.x * 256 + threadIdx.x;
    sm[threadIdx.x] = deg[i];
    __syncthreads();
    for (int s = 128; s > 0; s >>= 1) {
        if (threadIdx.x < s) sm[threadIdx.x] += sm[threadIdx.x + s];
        __syncthreads();
    }
    if (threadIdx.x == 0) bsum[blockIdx.x] = sm[0];
}

__global__ void k_scan_bsum(const int* __restrict__ bsum, int* __restrict__ boff)
{
    __shared__ int sm[1024];
    int t = threadIdx.x;
    int v = (t < 800) ? bsum[t] : 0;
    sm[t] = v;
    __syncthreads();
    for (int o = 1; o < 1024; o <<= 1) {
        int add = (t >= o) ? sm[t - o] : 0;
        __syncthreads();
        sm[t] += add;
        __syncthreads();
    }
    if (t < 800) boff[t] = sm[t] - v;   // exclusive
}

__global__ void k_scan_deg(const int* __restrict__ deg, const int* __restrict__ boff,
                           int* __restrict__ off)
{
    __shared__ int sm[256];
    int t = threadIdx.x;
    int i = blockIdx.x * 256 + t;
    int v = deg[i];
    sm[t] = v;
    __syncthreads();
    for (int o = 1; o < 256; o <<= 1) {
        int add = (t >= o) ? sm[t - o] : 0;
        __syncthreads();
        sm[t] += add;
        __syncthreads();
    }
    int incl = sm[t];
    int base = boff[blockIdx.x];
    off[i] = base + incl - v;
    if (i == NN - 1) off[NN] = base + incl;
}

// ---------------- K3: CSR fill ---------------------------------------------
__global__ void k_fill(const int* __restrict__ int_dst, const int* __restrict__ off,
                       int* __restrict__ cursor, int* __restrict__ e_sorted)
{
    int e = blockIdx.x * 256 + threadIdx.x;
    int d = int_dst[e];
    int slot = atomicAdd(&cursor[d], 1);
    e_sorted[off[d] + slot] = e;
}

// ---------------- K4: per-dst softmax + ft gather (wave per dst) -----------
__global__ __launch_bounds__(256) void k_softmax_ft(
    const u16* __restrict__ emb_bf, const int* __restrict__ iid,
    const int* __restrict__ int_src, const float* __restrict__ logits,
    const int* __restrict__ off, const int* __restrict__ e_sorted,
    u16* __restrict__ ft)
{
    int dst = blockIdx.x * 4 + (threadIdx.x >> 6);
    int lane = threadIdx.x & 63;
    int s0 = off[dst], s1 = off[dst + 1];
    u32* out = (u32*)(ft + (size_t)dst * DIM);
    if (s0 == s1) { out[lane] = 0u; return; }
    float m = -1e30f;
    for (int i = s0; i < s1; i++) m = fmaxf(m, logits[e_sorted[i]]);
    float ssum = 0.f, ax = 0.f, ay = 0.f;
    for (int i = s0; i < s1; i++) {
        int e = e_sorted[i];
        float w = __expf(logits[e] - m);
        ssum += w;
        int row = iid[int_src[e]];
        ushort2 u = ((const ushort2*)(emb_bf + (size_t)row * DIM))[lane];
        ax += w * b2f(u.x);
        ay += w * b2f(u.y);
    }
    float inv = 1.f / ssum;
    out[lane] = (u32)f2b(ax * inv) | ((u32)f2b(ay * inv) << 16);
}

// ---------------- K5: session mean + f = [h_t, mean] @ r_w^T ---------------
__global__ __launch_bounds__(128) void k_mean_f(
    const u16* __restrict__ ft, const float* __restrict__ target_emb,
    const float* __restrict__ r_w, const int* __restrict__ tid,
    float* __restrict__ fmat)
{
    __shared__ float sht[DIM], smean[DIM];
    int b = blockIdx.x, t = threadIdx.x;
    size_t j0 = (size_t)b * LL;
    float s = 0.f;
    for (int i = 0; i < LL; i++) s += b2f(ft[(j0 + i) * DIM + t]);
    smean[t] = s * (1.f / (float)LL);
    sht[t] = target_emb[(size_t)tid[b] * DIM + t];
    __syncthreads();
    const float2* rw = (const float2*)(r_w + (size_t)t * 2 * DIM);
    float acc = 0.f;
    #pragma unroll 8
    for (int k = 0; k < 64; k++) {
        float2 u = rw[k];
        acc += sht[2 * k] * u.x + sht[2 * k + 1] * u.y;
    }
    #pragma unroll 8
    for (int k = 0; k < 64; k++) {
        float2 u = rw[64 + k];
        acc += smean[2 * k] * u.x + smean[2 * k + 1] * u.y;
    }
    fmat[(size_t)b * DIM + t] = acc;
}

// ---------------- K6: fused e2-GEMM + tanh + coef (MFMA) -------------------
// A[j, 0:256] = [ft[j] | pos_emb[pid[j]]], W = q_w[128,256]; coef[j]=tanh(AW^T)·f[sess]
#define K6_STRIDE 136   // u16 per LDS row (128 data + 8 pad), 16B aligned
__global__ __launch_bounds__(256) void k_coef(
    const u16* __restrict__ ft, const u16* __restrict__ pos_bf,
    const u16* __restrict__ qw_bf, const int* __restrict__ pid,
    const int* __restrict__ agg_dst, const float* __restrict__ fmat,
    float* __restrict__ coef)
{
    extern __shared__ u16 smA[];    // 128 x K6_STRIDE
    int j0 = blockIdx.x * 128;
    int t = threadIdx.x;
    int wave = t >> 6, lane = t & 63, quad = lane >> 4, col = lane & 15;
    int m0 = wave * 32;

    f32x4 acc[2][8];
    #pragma unroll
    for (int mt = 0; mt < 2; mt++)
        #pragma unroll
        for (int nt = 0; nt < 8; nt++)
            acc[mt][nt] = (f32x4){0.f, 0.f, 0.f, 0.f};

    for (int h = 0; h < 2; h++) {          // K halves: ft then pos
        __syncthreads();
        {   // stage 128 rows x 128 el
            int r = t >> 1;
            int j = j0 + r;
            const u16* src = h ? (pos_bf + (size_t)pid[j] * DIM)
                               : (ft + (size_t)j * DIM);
            const uint4* s4 = (const uint4*)src;
            uint4* d4 = (uint4*)(smA + r * K6_STRIDE);
            int c0 = (t & 1) * 8;
            #pragma unroll
            for (int c = 0; c < 8; c++) d4[c0 + c] = s4[c0 + c];
        }
        __syncthreads();
        #pragma unroll
        for (int kk = 0; kk < 4; kk++) {
            int koff = kk * 32 + quad * 8;          // within this half
            short8 a0 = *(const short8*)(smA + (m0 + col) * K6_STRIDE + koff);
            short8 a1 = *(const short8*)(smA + (m0 + 16 + col) * K6_STRIDE + koff);
            #pragma unroll
            for (int nt = 0; nt < 8; nt++) {
                short8 b = *(const short8*)(qw_bf + (size_t)(nt * 16 + col) * 2 * DIM
                                            + h * DIM + koff);
                acc[0][nt] = __builtin_amdgcn_mfma_f32_16x16x32_bf16(a0, b, acc[0][nt], 0, 0, 0);
                acc[1][nt] = __builtin_amdgcn_mfma_f32_16x16x32_bf16(a1, b, acc[1][nt], 0, 0, 0);
            }
        }
    }

    // epilogue: coef[j] = sum_n tanh(e2)*f[sess][n]
    #pragma unroll
    for (int mt = 0; mt < 2; mt++) {
        float part[4];
        #pragma unroll
        for (int reg = 0; reg < 4; reg++) {
            int jrow = j0 + m0 + mt * 16 + quad * 4 + reg;
            int sess = agg_dst[jrow];
            const float* fr = fmat + (size_t)sess * DIM;
            float p = 0.f;
            #pragma unroll
            for (int nt = 0; nt < 8; nt++) {
                float x = acc[mt][nt][reg];
                x = fminf(fmaxf(x, -15.f), 15.f);
                float e2x = __expf(2.f * x);
                float th = (e2x - 1.f) / (e2x + 1.f);
                p += th * fr[nt * 16 + col];
            }
            part[reg] = p;
        }
        #pragma unroll
        for (int o = 1; o < 16; o <<= 1)
            #pragma unroll
            for (int reg = 0; reg < 4; reg++)
                part[reg] += __shfl_xor(part[reg], o, 64);
        if (col == 0) {
            #pragma unroll
            for (int reg = 0; reg < 4; reg++)
                coef[j0 + m0 + mt * 16 + quad * 4 + reg] = part[reg];
        }
    }
}

// ---------------- K7: select[b] = sum_j ft[j]*coef[j] ----------------------
__global__ __launch_bounds__(128) void k_select(
    const u16* __restrict__ ft, const float* __restrict__ coef,
    u16* __restrict__ selectb)
{
    int b = blockIdx.x, t = threadIdx.x;
    size_t j0 = (size_t)b * LL;
    float s = 0.f;
    for (int i = 0; i < LL; i++) {
        size_t j = j0 + i;
        s += coef[j] * b2f(ft[j * DIM + t]);
    }
    selectb[(size_t)b * DIM + t] = f2b(s);
}

// ---------------- K8: scores = select @ emb[1:]^T (MFMA, fp32 out) ---------
#define K8_STRIDE 136
__global__ __launch_bounds__(256) void k_scores(
    const u16* __restrict__ selectb, const u16* __restrict__ emb_bf,
    float* __restrict__ out)
{
    extern __shared__ u16 sm[];     // 128 x K8_STRIDE
    int n0 = blockIdx.x * 128;      // score column tile
    int m0v = blockIdx.y * 128;     // session row tile
    int t = threadIdx.x;
    {   // stage A tile (select rows)
        int r = t >> 1;
        const uint4* s4 = (const uint4*)(selectb + (size_t)(m0v + r) * DIM);
        uint4* d4 = (uint4*)(sm + r * K8_STRIDE);
        int c0 = (t & 1) * 8;
        #pragma unroll
        for (int c = 0; c < 8; c++) d4[c0 + c] = s4[c0 + c];
    }
    __syncthreads();
    int wave = t >> 6, lane = t & 63, quad = lane >> 4, col = lane & 15;
    int m0 = wave * 32;
    f32x4 acc[2][8];
    #pragma unroll
    for (int mt = 0; mt < 2; mt++)
        #pragma unroll
        for (int nt = 0; nt < 8; nt++)
            acc[mt][nt] = (f32x4){0.f, 0.f, 0.f, 0.f};

    #pragma unroll
    for (int kk = 0; kk < 4; kk++) {
        int koff = kk * 32 + quad * 8;
        short8 a0 = *(const short8*)(sm + (m0 + col) * K8_STRIDE + koff);
        short8 a1 = *(const short8*)(sm + (m0 + 16 + col) * K8_STRIDE + koff);
        #pragma unroll
        for (int nt = 0; nt < 8; nt++) {
            int v = n0 + nt * 16 + col;
            int er = v + 1;
            if (er > NV) er = NV;           // clamp tail reads (emb row 43096 valid)
            short8 b = *(const short8*)(emb_bf + (size_t)er * DIM + koff);
            acc[0][nt] = __builtin_amdgcn_mfma_f32_16x16x32_bf16(a0, b, acc[0][nt], 0, 0, 0);
            acc[1][nt] = __builtin_amdgcn_mfma_f32_16x16x32_bf16(a1, b, acc[1][nt], 0, 0, 0);
        }
    }
    // direct fp32 stores from C-layout: 16 consecutive cols per quad (64B sectors)
    #pragma unroll
    for (int mt = 0; mt < 2; mt++)
        #pragma unroll
        for (int reg = 0; reg < 4; reg++) {
            int row = m0v + m0 + mt * 16 + quad * 4 + reg;
            float* orow = out + (size_t)row * NV;
            #pragma unroll
            for (int nt = 0; nt < 8; nt++) {
                int v = n0 + nt * 16 + col;
                if (v < NV) orow[v] = acc[mt][nt][reg];
            }
        }
}

// ---------------- launch ---------------------------------------------------
extern "C" void kernel_launch(void* const* d_in, const int* in_sizes, int n_in,
                              void* d_out, int out_size, void* d_ws, size_t ws_size,
                              hipStream_t stream)
{
    const float* emb        = (const float*)d_in[0];
    const float* pos_emb    = (const float*)d_in[1];
    const float* target_emb = (const float*)d_in[2];
    const float* pi_w       = (const float*)d_in[3];
    const float* q_w        = (const float*)d_in[4];
    const float* r_w        = (const float*)d_in[5];
    const int* iid          = (const int*)d_in[6];
    const int* pid          = (const int*)d_in[7];
    const int* tid          = (const int*)d_in[8];
    const int* int_src      = (const int*)d_in[9];
    const int* int_dst      = (const int*)d_in[10];
    const int* agg_dst      = (const int*)d_in[12];
    float* out = (float*)d_out;

    char* ws = (char*)d_ws;
    u16*   emb_bf  = (u16*)  (ws + 0);                        // 43097*128*2 = 11,032,832
    u16*   pos_bf  = (u16*)  (ws + 11032832);                 // 200*128*2 = 51,200
    u16*   qw_bf   = (u16*)  (ws + 11084032);                 // 128*256*2 = 65,536
    float* logits  = (float*)(ws + 11149568);                 // E*4
    int*   deg     = (int*)  (ws + 14426368);                 // N*4
    int*   off     = (int*)  (ws + 15245568);                 // (N+1)*4
    int*   cursor  = (int*)  (ws + 16065024);                 // N*4
    int*   bsum    = (int*)  (ws + 16884224);                 // 800*4
    int*   boff    = (int*)  (ws + 16887424);                 // 800*4
    int*   e_sorted= (int*)  (ws + 16890880);                 // E*4
    u16*   ft      = (u16*)  (ws + 20167680);                 // N*128*2
    float* fmat    = (float*)(ws + 72596480);                 // B*128*4
    float* coef    = (float*)(ws + 74693632);                 // N*4
    u16*   selectb = (u16*)  (ws + 75512832);                 // B*128*2  (ends 76,561,408)

    hipMemsetAsync(deg, 0, NN * sizeof(int), stream);
    hipMemsetAsync(cursor, 0, NN * sizeof(int), stream);

    k_cvt<<<(NUM_NODE * DIM / 2 + 255) / 256, 256, 0, stream>>>(emb, emb_bf, NUM_NODE * DIM / 2);
    k_cvt<<<(200 * DIM / 2 + 255) / 256, 256, 0, stream>>>(pos_emb, pos_bf, 200 * DIM / 2);
    k_cvt<<<(DIM * 2 * DIM / 2 + 255) / 256, 256, 0, stream>>>(q_w, qw_bf, DIM * 2 * DIM / 2);

    k_edge_logits<<<EE / 4, 256, 0, stream>>>(emb_bf, pi_w, iid, int_src, int_dst, logits, deg);
    k_block_sum<<<NN / 256, 256, 0, stream>>>(deg, bsum);
    k_scan_bsum<<<1, 1024, 0, stream>>>(bsum, boff);
    k_scan_deg<<<NN / 256, 256, 0, stream>>>(deg, boff, off);
    k_fill<<<EE / 256, 256, 0, stream>>>(int_dst, off, cursor, e_sorted);
    k_softmax_ft<<<NN / 4, 256, 0, stream>>>(emb_bf, iid, int_src, logits, off, e_sorted, ft);
    k_mean_f<<<BB, 128, 0, stream>>>(ft, target_emb, r_w, tid, fmat);
    k_coef<<<NN / 128, 256, 128 * K6_STRIDE * 2, stream>>>(ft, pos_bf, qw_bf, pid, agg_dst, fmat, coef);
    k_select<<<BB, 128, 0, stream>>>(ft, coef, selectb);
    dim3 g8((NV + 127) / 128, BB / 128);
    k_scores<<<g8, 256, 128 * K8_STRIDE * 2, stream>>>(selectb, emb_bf, out);
}